// Round 1
// 957.451 us; speedup vs baseline: 2.4974x; 2.4974x over previous
//
#include <hip/hip_runtime.h>
#include <math.h>

// Problem constants (B=2, S=512, H=2048, E=16, I=1408, top_k=4, keep_k=2)
#define NTOK 1024
#define HD   2048
#define NE   16
#define ID   1408
#define CAP  1024      // per-expert token capacity (worst case)
#define BT   64        // token tile (M)
#define BK   32        // k step (one 16x16x32 MFMA)
#define LROW 33        // LDS row stride in uints (32 + 1 pad -> 2-way banks both directions)

// Workspace layout (4-byte units):
//  [0,16)                     counts[E]
//  [16,33)                    offsets[E+1]
//  [64, 64+E*CAP)             tok_list
//  [64+E*CAP, 64+2*E*CAP)     wt_list
//  [ACT_OFF, ...)             act[2048][ID] packed (bf16hi<<16 | bf16lo)
#define TOK_OFF 64
#define WT_OFF  (TOK_OFF + NE * CAP)
#define ACT_OFF (WT_OFF + NE * CAP)

typedef __attribute__((ext_vector_type(8))) short bf16x8;   // 8 bf16 (4 VGPRs)
typedef __attribute__((ext_vector_type(4))) float f32x4;
typedef unsigned int u32;

// split fp32 -> (bf16 hi | bf16 lo) packed in one uint. hi = truncated top 16 bits,
// lo = bf16(x - hi). x ~= hi + lo to ~2^-16 relative.
__device__ __forceinline__ u32 pack_hilo(float x) {
    u32 b  = __builtin_bit_cast(u32, x);
    u32 hb = b & 0xFFFF0000u;
    float lo = x - __builtin_bit_cast(float, hb);
    return hb | (__builtin_bit_cast(u32, lo) >> 16);
}

__device__ __forceinline__ void unpack_frag(const u32* p, bf16x8& hi, bf16x8& lo) {
    bf16x8 h, l;
    #pragma unroll
    for (int j = 0; j < 8; ++j) {
        u32 q = p[j];
        h[j] = (short)(q >> 16);
        l[j] = (short)(q & 0xFFFFu);
    }
    hi = h; lo = l;
}

__device__ __forceinline__ f32x4 mfma16(bf16x8 a, bf16x8 b, f32x4 c) {
    return __builtin_amdgcn_mfma_f32_16x16x32_bf16(a, b, c, 0, 0, 0);
}

__global__ void router_kernel(const float* __restrict__ x,
                              const float* __restrict__ gw,
                              int* __restrict__ counts,
                              int* __restrict__ tok_list,
                              float* __restrict__ wt_list) {
    int n = blockIdx.x;
    int lane = threadIdx.x;           // 64 threads = 1 wave
    const float* xr = x + (size_t)n * HD;
    __shared__ float slog[NE];
    for (int e = 0; e < NE; ++e) {
        const float* g = gw + (size_t)e * HD;
        float p = 0.f;
        for (int h = lane; h < HD; h += 64) p = fmaf(xr[h], g[h], p);
        #pragma unroll
        for (int off = 32; off > 0; off >>= 1) p += __shfl_xor(p, off, 64);
        if (lane == 0) slog[e] = p;
    }
    __syncthreads();
    if (lane == 0) {
        int i1 = -1, i2 = -1;
        float m1 = -1e30f, m2 = -1e30f;
        for (int e = 0; e < NE; ++e) {
            float v = slog[e];
            if (v > m1) { m2 = m1; i2 = i1; m1 = v; i1 = e; }
            else if (v > m2) { m2 = v; i2 = e; }
        }
        float w1 = 1.f / (1.f + expf(m2 - m1));
        float w2 = 1.f - w1;
        int s1 = atomicAdd(&counts[i1], 1);
        tok_list[i1 * CAP + s1] = n;
        wt_list[i1 * CAP + s1] = w1;
        int s2 = atomicAdd(&counts[i2], 1);
        tok_list[i2 * CAP + s2] = n;
        wt_list[i2 * CAP + s2] = w2;
    }
}

__global__ void prefix_kernel(const int* __restrict__ counts, int* __restrict__ offsets) {
    if (threadIdx.x == 0 && blockIdx.x == 0) {
        int s = 0;
        for (int e = 0; e < NE; ++e) { offsets[e] = s; s += counts[e]; }
        offsets[NE] = s;
    }
}

// Phase A (MFMA): act[slot][i] = pack(silu(x·Wg)·(x·Wu)) for a 64-token x 64-i tile.
// grid: (ID/64=22, CAP/BT=16, NE=16), block 256 = 4 waves (2M x 2N of 32x32)
__global__ __launch_bounds__(256) void gateup_mfma(
    const float* __restrict__ x,
    const float* __restrict__ wg, const float* __restrict__ wu,
    const int* __restrict__ counts, const int* __restrict__ offsets,
    const int* __restrict__ tok_list, u32* __restrict__ act) {
    int e = blockIdx.z;
    int cnt = counts[e];
    int t0 = blockIdx.y * BT;
    if (t0 >= cnt) return;
    int tlim = min(BT, cnt - t0);
    int base = offsets[e] + t0;
    int i0 = blockIdx.x * 64;

    __shared__ u32 lA[BT * LROW];   // x tile     [t][k] packed hi|lo
    __shared__ u32 lG[64 * LROW];   // Wg tile    [i][k] (transposed store)
    __shared__ u32 lU[64 * LROW];   // Wu tile    [i][k]
    __shared__ int stok[BT];

    int tid = threadIdx.x;
    if (tid < BT) stok[tid] = (tid < tlim) ? tok_list[e * CAP + t0 + tid] : 0;

    int lane = tid & 63;
    int w  = tid >> 6;
    int wm = w >> 1;            // token half (0/1)
    int wn = w & 1;             // col half (0/1)
    int lr = lane & 15;
    int kg = (lane >> 4) * 8;   // k-group within the 32-k tile

    f32x4 accg[2][2], accu[2][2];
    #pragma unroll
    for (int f = 0; f < 2; ++f)
        #pragma unroll
        for (int g = 0; g < 2; ++g) { accg[f][g] = (f32x4)(0.f); accu[f][g] = (f32x4)(0.f); }

    const float* wge = wg + (size_t)e * HD * ID;
    const float* wue = wu + (size_t)e * HD * ID;

    // staging assignments
    int sh = tid & 31, stb = tid >> 5;          // A: h in [0,32), t = stb + 8r
    int si = tid & 63, skb = tid >> 6;          // B: i in [0,64), k = skb + 4r

    for (int h0 = 0; h0 < HD; h0 += BK) {
        __syncthreads();
        #pragma unroll
        for (int r = 0; r < 8; ++r) {
            int t = stb + 8 * r;
            lA[t * LROW + sh] = pack_hilo(x[(size_t)stok[t] * HD + h0 + sh]);
        }
        {
            const float* pg = wge + (size_t)h0 * ID + i0 + si;
            const float* pu = wue + (size_t)h0 * ID + i0 + si;
            #pragma unroll
            for (int r = 0; r < 8; ++r) {
                int k = skb + 4 * r;
                lG[si * LROW + k] = pack_hilo(pg[(size_t)k * ID]);
                lU[si * LROW + k] = pack_hilo(pu[(size_t)k * ID]);
            }
        }
        __syncthreads();

        bf16x8 ah[2], al[2], gh[2], gl[2], uh[2], ul[2];
        #pragma unroll
        for (int f = 0; f < 2; ++f) {
            int arow = wm * 32 + f * 16 + lr;
            unpack_frag(&lA[arow * LROW + kg], ah[f], al[f]);
            int bcol = wn * 32 + f * 16 + lr;
            unpack_frag(&lG[bcol * LROW + kg], gh[f], gl[f]);
            unpack_frag(&lU[bcol * LROW + kg], uh[f], ul[f]);
        }
        #pragma unroll
        for (int f = 0; f < 2; ++f)
            #pragma unroll
            for (int g = 0; g < 2; ++g) {
                accg[f][g] = mfma16(ah[f], gh[g], accg[f][g]);
                accg[f][g] = mfma16(ah[f], gl[g], accg[f][g]);
                accg[f][g] = mfma16(al[f], gh[g], accg[f][g]);
                accu[f][g] = mfma16(ah[f], uh[g], accu[f][g]);
                accu[f][g] = mfma16(ah[f], ul[g], accu[f][g]);
                accu[f][g] = mfma16(al[f], uh[g], accu[f][g]);
            }
    }

    // epilogue: C/D layout row=(lane>>4)*4+r, col=lane&15 (guide-verified)
    #pragma unroll
    for (int f = 0; f < 2; ++f)
        #pragma unroll
        for (int g = 0; g < 2; ++g)
            #pragma unroll
            for (int r = 0; r < 4; ++r) {
                int trow = wm * 32 + f * 16 + (lane >> 4) * 4 + r;
                if (trow < tlim) {
                    int icol = i0 + wn * 32 + g * 16 + lr;
                    float gv = accg[f][g][r];
                    float uv = accu[f][g][r];
                    float a = (gv / (1.f + __expf(-gv))) * uv;
                    act[(size_t)(base + trow) * ID + icol] = pack_hilo(a);
                }
            }
}

// Phase B (MFMA): out[n][h] += wt * (act · Wd) for a 64-token x 64-h tile.
// grid: (HD/64=32, CAP/BT=16, NE=16), block 256
__global__ __launch_bounds__(256) void down_mfma(
    const float* __restrict__ wd,
    const int* __restrict__ counts, const int* __restrict__ offsets,
    const int* __restrict__ tok_list, const float* __restrict__ wt_list,
    const u32* __restrict__ act, float* __restrict__ out) {
    int e = blockIdx.z;
    int cnt = counts[e];
    int t0 = blockIdx.y * BT;
    if (t0 >= cnt) return;
    int tlim = min(BT, cnt - t0);
    int base = offsets[e] + t0;
    int h0 = blockIdx.x * 64;

    __shared__ u32 lA[BT * LROW];   // act tile [t][k] (already packed)
    __shared__ u32 lB[64 * LROW];   // Wd tile  [h][k] (transposed store)
    __shared__ int   stok[BT];
    __shared__ float swt[BT];

    int tid = threadIdx.x;
    if (tid < BT) {
        int ok = tid < tlim;
        stok[tid] = ok ? tok_list[e * CAP + t0 + tid] : 0;
        swt[tid]  = ok ? wt_list[e * CAP + t0 + tid] : 0.f;
    }

    int lane = tid & 63;
    int w  = tid >> 6;
    int wm = w >> 1;
    int wn = w & 1;
    int lr = lane & 15;
    int kg = (lane >> 4) * 8;

    f32x4 acc[2][2];
    #pragma unroll
    for (int f = 0; f < 2; ++f)
        #pragma unroll
        for (int g = 0; g < 2; ++g) acc[f][g] = (f32x4)(0.f);

    const float* wde = wd + (size_t)e * ID * HD;

    int aq = tid & 7, atr = tid >> 3;          // A: 4-uint chunk q, row tr (+32)
    int sh = tid & 63, skb = tid >> 6;         // B: h col, k = skb + 4r

    for (int i0 = 0; i0 < ID; i0 += BK) {      // 44 iterations
        __syncthreads();
        #pragma unroll
        for (int rp = 0; rp < 2; ++rp) {
            int t = atr + 32 * rp;
            uint4 v = {0u, 0u, 0u, 0u};
            if (t < tlim)
                v = *(const uint4*)&act[(size_t)(base + t) * ID + i0 + aq * 4];
            int dst = t * LROW + aq * 4;
            lA[dst + 0] = v.x; lA[dst + 1] = v.y; lA[dst + 2] = v.z; lA[dst + 3] = v.w;
        }
        {
            const float* pd = wde + (size_t)i0 * HD + h0 + sh;
            #pragma unroll
            for (int r = 0; r < 8; ++r) {
                int k = skb + 4 * r;
                lB[sh * LROW + k] = pack_hilo(pd[(size_t)k * HD]);
            }
        }
        __syncthreads();

        bf16x8 ah[2], al[2], bh[2], bl[2];
        #pragma unroll
        for (int f = 0; f < 2; ++f) {
            int arow = wm * 32 + f * 16 + lr;
            unpack_frag(&lA[arow * LROW + kg], ah[f], al[f]);
            int bcol = wn * 32 + f * 16 + lr;
            unpack_frag(&lB[bcol * LROW + kg], bh[f], bl[f]);
        }
        #pragma unroll
        for (int f = 0; f < 2; ++f)
            #pragma unroll
            for (int g = 0; g < 2; ++g) {
                acc[f][g] = mfma16(ah[f], bh[g], acc[f][g]);
                acc[f][g] = mfma16(ah[f], bl[g], acc[f][g]);
                acc[f][g] = mfma16(al[f], bh[g], acc[f][g]);
            }
    }

    #pragma unroll
    for (int f = 0; f < 2; ++f)
        #pragma unroll
        for (int g = 0; g < 2; ++g)
            #pragma unroll
            for (int r = 0; r < 4; ++r) {
                int trow = wm * 32 + f * 16 + (lane >> 4) * 4 + r;
                if (trow < tlim) {
                    int hcol = h0 + wn * 32 + g * 16 + lr;
                    atomicAdd(&out[(size_t)stok[trow] * HD + hcol], swt[trow] * acc[f][g][r]);
                }
            }
}

extern "C" void kernel_launch(void* const* d_in, const int* in_sizes, int n_in,
                              void* d_out, int out_size, void* d_ws, size_t ws_size,
                              hipStream_t stream) {
    const float* x  = (const float*)d_in[0];
    const float* gw = (const float*)d_in[1];
    const float* wg = (const float*)d_in[2];
    const float* wu = (const float*)d_in[3];
    const float* wd = (const float*)d_in[4];
    // d_in[5]=top_k(4), d_in[6]=keep_k(2) — fixed by problem, hard-coded.

    int*   counts   = (int*)d_ws;
    int*   offsets  = counts + NE;
    int*   tok_list = (int*)d_ws + TOK_OFF;
    float* wt_list  = (float*)d_ws + WT_OFF;
    u32*   act      = (u32*)d_ws + ACT_OFF;
    float* out      = (float*)d_out;

    hipMemsetAsync(counts, 0, NE * sizeof(int), stream);
    hipMemsetAsync(out, 0, (size_t)out_size * sizeof(float), stream);

    router_kernel<<<NTOK, 64, 0, stream>>>(x, gw, counts, tok_list, wt_list);
    prefix_kernel<<<1, 64, 0, stream>>>(counts, offsets);

    dim3 gA(ID / 64, CAP / BT, NE);   // 22 x 16 x 16
    gateup_mfma<<<gA, 256, 0, stream>>>(x, wg, wu, counts, offsets, tok_list, act);

    dim3 gB(HD / 64, CAP / BT, NE);   // 32 x 16 x 16
    down_mfma<<<gB, 256, 0, stream>>>(wd, counts, offsets, tok_list, wt_list, act, out);
}